// Round 2
// baseline (772.948 us; speedup 1.0000x reference)
//
#include <hip/hip_runtime.h>

typedef short v8s __attribute__((ext_vector_type(8)));
typedef float v4f __attribute__((ext_vector_type(4)));

// problem constants
#define NCH    64
#define NHH    128
#define NWW    128
#define NOC    64
#define KSTEPS 18          // 576 / 32

// LDS slab layout: [6 rows][66 cols][72 c (64 + 8 pad)] bf16
#define CSTR 72
#define COLS 66
#define SLAB_BYTES (6 * COLS * CSTR * 2)     // 57024
#define LDSG_OFF   69632                     // gates after transpose region
#define SMEM_BYTES 70144

#define GW_STRIDE 6144

__device__ __forceinline__ unsigned short f2bf(float f) {
  unsigned int u = __float_as_uint(f);
  u += 0x7FFFu + ((u >> 16) & 1u);           // round-to-nearest-even
  return (unsigned short)(u >> 16);
}

// ---------------------------------------------------------------------------
// Pack expert weights into MFMA B-fragment-linear bf16:
// element (((e*18+s)*4+nt)*64+lane)*8+j  =  W[k = s*32+(lane>>4)*8+j][n = nt*16+(lane&15)]
// with k = (kh*3+kw)*64 + c  and W[k][n] = expert_w[e][n][c][kh][kw]
// Total elements: 8*18*4*64*8 = 294912
// ---------------------------------------------------------------------------
__global__ void pack_b_kernel(const float* __restrict__ ew,
                              unsigned short* __restrict__ bp) {
  int f = blockIdx.x * 256 + threadIdx.x;    // 0 .. 294911
  int j = f & 7;
  int t = f >> 3;
  int lane = t & 63;
  t >>= 6;
  int nt = t & 3;
  t >>= 2;                                   // t = e*18 + s, 0..143
  int s = t % KSTEPS;
  int e = t / KSTEPS;
  int k = s * 32 + (lane >> 4) * 8 + j;
  int n = nt * 16 + (lane & 15);
  int khw = k >> 6;
  int c = k & 63;
  bp[f] = f2bf(ew[((e * NOC + n) * NCH + c) * 9 + khw]);
}

// ---------------------------------------------------------------------------
// Gating v2: one block per (b, ph) = 256 blocks x 512 threads (8 waves).
// Wave w == expert w. x slab (64ch x 8rows x 128cols) staged through LDS in
// 4 chunks of 16 channels; each gw float4 loaded ONCE per block and reused
// across all 16 patches (pw). Positional part folded to precomputed per-
// feature row-sums (feature is constant over the 64 patch pixels).
// ---------------------------------------------------------------------------
__global__ __launch_bounds__(512) void gate_kernel(
    const float* __restrict__ x,
    const float* __restrict__ gw,
    const float* __restrict__ gb,
    float* __restrict__ gate_out) {
  __shared__ float xs[16][8][132];   // 16-ch chunk, 8 rows, 128 cols (+4 pad)
  __shared__ float wsum[8][32];      // pos-part row sums per (expert, feature)
  __shared__ float lg[16][8];        // logits [pw][e]

  const int pid = blockIdx.x;        // b*16 + ph
  const int ph = pid & 15;
  const int b = pid >> 4;
  const int tid = threadIdx.x;
  const int e = tid >> 6;            // expert = wave id
  const int lane = tid & 63;

  // positional row-sums: 256 threads cover (e2, j) = 8 x 32
  if (tid < 256) {
    int e2 = tid >> 5, j = tid & 31;
    const float* p = gw + e2 * GW_STRIDE + 4096 + j * 64;
    float s = 0.f;
#pragma unroll
    for (int g = 0; g < 16; ++g) {
      float4 v = *(const float4*)(p + g * 4);
      s += v.x + v.y + v.z + v.w;
    }
    wsum[e2][j] = s;
  }

  float acc[16];
#pragma unroll
  for (int pw = 0; pw < 16; ++pw) acc[pw] = 0.f;

  const float* xrow = x + ((size_t)(b * NCH) * NHH + ph * 8) * NWW;

  for (int cc = 0; cc < 4; ++cc) {
    __syncthreads();                 // prior chunk fully consumed
    // stage 16 channels x 8 rows x 128 cols = 4096 float4 units, coalesced
    for (int i = tid; i < 4096; i += 512) {
      int c = i >> 8;
      int py = (i >> 5) & 7;
      int w4 = i & 31;
      float4 v = *(const float4*)&xrow[(cc * 16 + c) * (NHH * NWW) + py * NWW + w4 * 4];
      *(float4*)&xs[c][py][w4 * 4] = v;
    }
    __syncthreads();
    // each lane: 4 float4 k-groups of this chunk, reused across 16 patches
#pragma unroll
    for (int i = 0; i < 4; ++i) {
      int g = lane + 64 * i;         // 0..255 = (c:16, py:8, pxg:2)
      int pxg = g & 1;
      int py = (g >> 1) & 7;
      int c = g >> 4;
      const float4 wv = *(const float4*)&gw[e * GW_STRIDE + (cc * 16 + c) * 64 + py * 8 + pxg * 4];
      const float* xp = &xs[c][py][pxg * 4];
#pragma unroll
      for (int pw = 0; pw < 16; ++pw) {
        float4 xv = *(const float4*)(xp + pw * 8);
        acc[pw] += xv.x * wv.x + xv.y * wv.y + xv.z * wv.z + xv.w * wv.w;
      }
    }
  }

  // full-wave reduction: wave == expert, sum k-partials over 64 lanes
#pragma unroll
  for (int pw = 0; pw < 16; ++pw) {
    float v = acc[pw];
#pragma unroll
    for (int off = 32; off > 0; off >>= 1) v += __shfl_xor(v, off, 64);
    if (lane == 0) lg[pw][e] = v;
  }
  __syncthreads();

  // softmax per patch: thread pw handles all 8 experts (+ pos part + bias)
  if (tid < 16) {
    const int pw = tid;
    const float cy = (ph + 0.5f) / 16.0f;
    const float cx = (pw + 0.5f) / 16.0f;
    float l[8];
#pragma unroll
    for (int ee = 0; ee < 8; ++ee) l[ee] = lg[pw][ee] + gb[ee];
    for (int j = 0; j < 32; ++j) {
      float freq = (float)(1 << (j & 7)) * 3.14159265358979323846f;
      float base = (j < 16) ? cy : cx;
      float a = base * freq;
      float v = ((j >> 3) & 1) ? cosf(a) : sinf(a);
#pragma unroll
      for (int ee = 0; ee < 8; ++ee) l[ee] += v * wsum[ee][j];
    }
    float mx = -1e30f;
#pragma unroll
    for (int ee = 0; ee < 8; ++ee) mx = fmaxf(mx, l[ee]);
    float sum = 0.f;
#pragma unroll
    for (int ee = 0; ee < 8; ++ee) { l[ee] = expf(l[ee] - mx); sum += l[ee]; }
    float inv = 1.0f / sum;
#pragma unroll
    for (int ee = 0; ee < 8; ++ee)
      gate_out[(pid * 16 + pw) * 8 + ee] = l[ee] * inv;   // [b][ph][pw][e]
  }
}

// ---------------------------------------------------------------------------
// Main fused kernel v2: block = 4 waves (256 thr), 4 rows x 64 cols x 64 oc.
// Wave (rp, och): rows hq*4 + rp*2 + {0,1}, oc half och (32 oc) -> M=128 N=32.
// B is NOT staged through LDS: bp is fragment-linear, so each wave streams
// its v8s B-fragments straight from L2 with global 16B loads. No barriers in
// the K-loop at all -> waves drift out of phase, loads stay in flight with
// compiler-counted vmcnt, and s_setprio(1) arbitrates MFMA-phase waves.
// A: sliding-window ds_read_b128 from the x slab (read-only after staging).
// ---------------------------------------------------------------------------
__global__ __launch_bounds__(256, 2) void moe_conv_kernel(
    const float* __restrict__ x,
    const float* __restrict__ eb,
    const unsigned short* __restrict__ bp,
    const float* __restrict__ gate,
    float* __restrict__ out) {
  __shared__ __align__(16) char smem[SMEM_BYTES];
  unsigned short* slab = (unsigned short*)smem;
  float* ldsg = (float*)(smem + LDSG_OFF);   // [pw_local 8][e 8]

  const int tid = threadIdx.x;
  const int bid = blockIdx.x;
  const int wseg = bid & 1;
  const int hq = (bid >> 1) & 31;
  const int b = bid >> 6;
  const int w0 = wseg * 64;
  const int wid = tid >> 6;
  const int lane = tid & 63;
  const int quad = lane >> 4;
  const int l15 = lane & 15;
  const int rp  = wid >> 1;         // row-pair within block
  const int och = wid & 1;          // oc half
  const int ntb = och * 2;          // base n-tile

  // gates for this block's 8 patches (4 rows = one patch row hq/2)
  if (tid < 64) {
    ldsg[tid] = gate[((b * 16 + (hq >> 1)) * 16 + wseg * 8 + (tid >> 3)) * 8 + (tid & 7)];
  }

  // --- stage x slab: rows hq*4-1 .. hq*4+4, cols w0-1 .. w0+64, all c ---
  const int hbase = hq * 4 - 1;
  const int wbase = w0 - 1;
  for (int flat = tid; flat < 6 * 32 * COLS; flat += 256) {
    int col = flat % COLS;
    int t = flat / COLS;
    int cp = t & 31;                    // channel pair
    int r = t >> 5;                     // slab row 0..5
    int gh = hbase + r;
    int gw_ = wbase + col;
    float v0 = 0.f, v1 = 0.f;
    if (((unsigned)gh < 128u) && ((unsigned)gw_ < 128u)) {
      const float* px = x + (((b * NCH + cp * 2) * NHH + gh) * NWW + gw_);
      v0 = px[0];
      v1 = px[NHH * NWW];
    }
    unsigned int pk = (unsigned int)f2bf(v0) | ((unsigned int)f2bf(v1) << 16);
    *(unsigned int*)&slab[(r * COLS + col) * CSTR + cp * 2] = pk;
  }
  __syncthreads();    // slab ready (only barrier before the epilogue)

  const v4f vzero = {0.f, 0.f, 0.f, 0.f};
  v4f oacc[8][2];
#pragma unroll
  for (int mt = 0; mt < 8; ++mt) {
    oacc[mt][0] = vzero;
    oacc[mt][1] = vzero;
  }

  // wave-constant part of the A-frag LDS address
  const unsigned short* abase = &slab[(rp * 2 * COLS + l15) * CSTR + quad * 8];
  // wave-constant part of the B-frag global address
  const unsigned short* bbase = bp + ntb * 512 + lane * 8;

  for (int e = 0; e < 8; ++e) {
    v4f vacc[8][2];
#pragma unroll
    for (int mt = 0; mt < 8; ++mt) {
      vacc[mt][0] = vzero;
      vacc[mt][1] = vzero;
    }

#pragma unroll
    for (int sl = 0; sl < KSTEPS; ++sl) {   // k-step within expert
      const int kh = sl / 6;
      const int kw = (sl / 2) % 3;
      const int ch = sl & 1;
      // B fragments straight from global (L2-resident, fragment-linear)
      const unsigned short* bsrc = bbase + (e * KSTEPS + sl) * 2048;
      const v8s b0 = *(const v8s*)(bsrc);
      const v8s b1 = *(const v8s*)(bsrc + 512);
      __builtin_amdgcn_s_setprio(1);
#pragma unroll
      for (int mt = 0; mt < 8; ++mt) {
        // row_local = rp*2 + (mt>>2) + kh ; col = (mt&3)*16 + l15 + kw
        const v8s a = *(const v8s*)(abase +
            (((mt >> 2) + kh) * COLS + (mt & 3) * 16 + kw) * CSTR + ch * 32);
        vacc[mt][0] = __builtin_amdgcn_mfma_f32_16x16x32_bf16(a, b0, vacc[mt][0], 0, 0, 0);
        vacc[mt][1] = __builtin_amdgcn_mfma_f32_16x16x32_bf16(a, b1, vacc[mt][1], 0, 0, 0);
      }
      __builtin_amdgcn_s_setprio(0);
    }

    // epilogue: bias + relu + gate, accumulate into oacc (wave-private)
    float bias0 = eb[e * NOC + ntb * 16 + l15];
    float bias1 = eb[e * NOC + (ntb + 1) * 16 + l15];
#pragma unroll
    for (int mt = 0; mt < 8; ++mt) {
      float g = ldsg[((mt & 3) * 2 + (quad >> 1)) * 8 + e];
#pragma unroll
      for (int r = 0; r < 4; ++r) {
        float v0 = fmaxf(vacc[mt][0][r] + bias0, 0.f);
        float v1 = fmaxf(vacc[mt][1][r] + bias1, 0.f);
        oacc[mt][0][r] += v0 * g;
        oacc[mt][1][r] += v1 * g;
      }
    }
  }

  // ---- transpose through LDS (per-wave region) for full-line stores ----
  __syncthreads();                      // all waves done reading the slab
  float* tb = (float*)smem + wid * 4352;  // [row:2][oc:32][68] floats = 17408 B
#pragma unroll
  for (int i = 0; i < 2; ++i)
#pragma unroll
    for (int mt = 0; mt < 8; ++mt)
      *(v4f*)(tb + (mt >> 2) * 2176 + (i * 16 + l15) * 68 + (mt & 3) * 16 + quad * 4) =
          oacc[mt][i];
  // wave-private region: in-wave lgkmcnt ordering suffices, no barrier

  const int h0 = hq * 4 + rp * 2;
#pragma unroll
  for (int r2 = 0; r2 < 2; ++r2) {
    const int h = h0 + r2;
#pragma unroll
    for (int g4 = 0; g4 < 8; ++g4) {
      const int ocl = g4 * 4 + quad;            // 0..31 within this oc half
      const v4f vv = *(const v4f*)(tb + r2 * 2176 + ocl * 68 + l15 * 4);
      float* dst = out + ((b * NOC + och * 32 + ocl) * NHH + h) * NWW + w0 + l15 * 4;
      *(v4f*)dst = vv;
    }
  }
}

// ---------------------------------------------------------------------------
extern "C" void kernel_launch(void* const* d_in, const int* in_sizes, int n_in,
                              void* d_out, int out_size, void* d_ws, size_t ws_size,
                              hipStream_t stream) {
  const float* x  = (const float*)d_in[0];
  const float* ew = (const float*)d_in[1];
  const float* eb = (const float*)d_in[2];
  const float* gw = (const float*)d_in[3];
  const float* gb = (const float*)d_in[4];
  float* out = (float*)d_out;

  unsigned short* bp = (unsigned short*)d_ws;              // 294912 bf16 = 589824 B
  float* gate = (float*)((char*)d_ws + 589824);            // 4096*8 fp32 = 131072 B

  hipLaunchKernelGGL(pack_b_kernel, dim3(1152), dim3(256), 0, stream, ew, bp);
  hipLaunchKernelGGL(gate_kernel, dim3(256), dim3(512), 0, stream, x, gw, gb, gate);
  hipLaunchKernelGGL(moe_conv_kernel, dim3(1024), dim3(256), 0, stream, x, eb, bp, gate, out);
}

// Round 3
// 293.331 us; speedup vs baseline: 2.6351x; 2.6351x over previous
//
#include <hip/hip_runtime.h>

typedef short v8s __attribute__((ext_vector_type(8)));
typedef float v4f __attribute__((ext_vector_type(4)));

// problem constants
#define NCH    64
#define NHH    128
#define NWW    128
#define NOC    64
#define KSTEPS 18          // 576 / 32

// LDS slab layout: [6 rows][66 cols][72 c (64 + 8 pad)] bf16
#define CSTR 72
#define COLS 66
#define SLAB_BYTES (6 * COLS * CSTR * 2)     // 57024
#define BBUF_OFF   SLAB_BYTES                // B double-buffer at 57024
#define LDSG_OFF   (SLAB_BYTES + 16384)      // gates at 73408
#define SMEM_BYTES 73728

#define GW_STRIDE 6144

__device__ __forceinline__ unsigned short f2bf(float f) {
  unsigned int u = __float_as_uint(f);
  u += 0x7FFFu + ((u >> 16) & 1u);           // round-to-nearest-even
  return (unsigned short)(u >> 16);
}

// ---------------------------------------------------------------------------
// Pack expert weights into MFMA B-fragment-linear bf16, EXPERT-PAIR order:
// stage gs = ep*18 + sl holds k-step sl for experts {2ep, 2ep+1}:
// element ((((gs*2 + e01)*4 + nt)*64 + lane)*8 + j
//   = W[e = 2ep+e01][k = sl*32+(lane>>4)*8+j][n = nt*16+(lane&15)]
// with k = (kh*3+kw)*64 + c and W[e][k][n] = expert_w[e][n][c][kh][kw]
// ---------------------------------------------------------------------------
__global__ void pack_b_kernel(const float* __restrict__ ew,
                              unsigned short* __restrict__ bp) {
  int f = blockIdx.x * 256 + threadIdx.x;    // 0 .. 294911
  int j = f & 7;
  int t = f >> 3;
  int lane = t & 63;
  t >>= 6;
  int nt = t & 3;
  t >>= 2;                                   // t = gs*2 + e01, 0..143
  int e01 = t & 1;
  int gs = t >> 1;                           // 0..71
  int sl = gs % KSTEPS;
  int ep = gs / KSTEPS;
  int e = ep * 2 + e01;
  int k = sl * 32 + (lane >> 4) * 8 + j;
  int n = nt * 16 + (lane & 15);
  int khw = k >> 6;
  int c = k & 63;
  bp[f] = f2bf(ew[((e * NOC + n) * NCH + c) * 9 + khw]);
}

// ---------------------------------------------------------------------------
// Gating v2 (unchanged, known-good): one block per (b, ph), 512 threads.
// ---------------------------------------------------------------------------
__global__ __launch_bounds__(512) void gate_kernel(
    const float* __restrict__ x,
    const float* __restrict__ gw,
    const float* __restrict__ gb,
    float* __restrict__ gate_out) {
  __shared__ float xs[16][8][132];   // 16-ch chunk, 8 rows, 128 cols (+4 pad)
  __shared__ float wsum[8][32];      // pos-part row sums per (expert, feature)
  __shared__ float lg[16][8];        // logits [pw][e]

  const int pid = blockIdx.x;        // b*16 + ph
  const int ph = pid & 15;
  const int b = pid >> 4;
  const int tid = threadIdx.x;
  const int e = tid >> 6;            // expert = wave id
  const int lane = tid & 63;

  // positional row-sums: 256 threads cover (e2, j) = 8 x 32
  if (tid < 256) {
    int e2 = tid >> 5, j = tid & 31;
    const float* p = gw + e2 * GW_STRIDE + 4096 + j * 64;
    float s = 0.f;
#pragma unroll
    for (int g = 0; g < 16; ++g) {
      float4 v = *(const float4*)(p + g * 4);
      s += v.x + v.y + v.z + v.w;
    }
    wsum[e2][j] = s;
  }

  float acc[16];
#pragma unroll
  for (int pw = 0; pw < 16; ++pw) acc[pw] = 0.f;

  const float* xrow = x + ((size_t)(b * NCH) * NHH + ph * 8) * NWW;

  for (int cc = 0; cc < 4; ++cc) {
    __syncthreads();                 // prior chunk fully consumed
    // stage 16 channels x 8 rows x 128 cols = 4096 float4 units, coalesced
    for (int i = tid; i < 4096; i += 512) {
      int c = i >> 8;
      int py = (i >> 5) & 7;
      int w4 = i & 31;
      float4 v = *(const float4*)&xrow[(cc * 16 + c) * (NHH * NWW) + py * NWW + w4 * 4];
      *(float4*)&xs[c][py][w4 * 4] = v;
    }
    __syncthreads();
    // each lane: 4 float4 k-groups of this chunk, reused across 16 patches
#pragma unroll
    for (int i = 0; i < 4; ++i) {
      int g = lane + 64 * i;         // 0..255 = (c:16, py:8, pxg:2)
      int pxg = g & 1;
      int py = (g >> 1) & 7;
      int c = g >> 4;
      const float4 wv = *(const float4*)&gw[e * GW_STRIDE + (cc * 16 + c) * 64 + py * 8 + pxg * 4];
      const float* xp = &xs[c][py][pxg * 4];
#pragma unroll
      for (int pw = 0; pw < 16; ++pw) {
        float4 xv = *(const float4*)(xp + pw * 8);
        acc[pw] += xv.x * wv.x + xv.y * wv.y + xv.z * wv.z + xv.w * wv.w;
      }
    }
  }

  // full-wave reduction: wave == expert, sum k-partials over 64 lanes
#pragma unroll
  for (int pw = 0; pw < 16; ++pw) {
    float v = acc[pw];
#pragma unroll
    for (int off = 32; off > 0; off >>= 1) v += __shfl_xor(v, off, 64);
    if (lane == 0) lg[pw][e] = v;
  }
  __syncthreads();

  // softmax per patch: thread pw handles all 8 experts (+ pos part + bias)
  if (tid < 16) {
    const int pw = tid;
    const float cy = (ph + 0.5f) / 16.0f;
    const float cx = (pw + 0.5f) / 16.0f;
    float l[8];
#pragma unroll
    for (int ee = 0; ee < 8; ++ee) l[ee] = lg[pw][ee] + gb[ee];
    for (int j = 0; j < 32; ++j) {
      float freq = (float)(1 << (j & 7)) * 3.14159265358979323846f;
      float base = (j < 16) ? cy : cx;
      float a = base * freq;
      float v = ((j >> 3) & 1) ? cosf(a) : sinf(a);
#pragma unroll
      for (int ee = 0; ee < 8; ++ee) l[ee] += v * wsum[ee][j];
    }
    float mx = -1e30f;
#pragma unroll
    for (int ee = 0; ee < 8; ++ee) mx = fmaxf(mx, l[ee]);
    float sum = 0.f;
#pragma unroll
    for (int ee = 0; ee < 8; ++ee) { l[ee] = expf(l[ee] - mx); sum += l[ee]; }
    float inv = 1.0f / sum;
#pragma unroll
    for (int ee = 0; ee < 8; ++ee)
      gate_out[(pid * 16 + pw) * 8 + ee] = l[ee] * inv;   // [b][ph][pw][e]
  }
}

// ---------------------------------------------------------------------------
// Async-stage one B stage (1 k-step x 2 experts = 8 KB) into LDS dbuf `buf`.
// Each wave DMAs its 2 KB quarter with two global_load_lds width-16 ops.
// ---------------------------------------------------------------------------
__device__ __forceinline__ void load_stage(const unsigned short* __restrict__ bp,
                                           char* smem, int gs, int buf,
                                           int wid, int lane) {
  const char* gsrc = (const char*)bp + gs * 8192 + wid * 2048 + lane * 16;
  char* ldst = smem + BBUF_OFF + buf * 8192 + wid * 2048;   // wave-uniform base
  __builtin_amdgcn_global_load_lds(
      (const __attribute__((address_space(1))) void*)gsrc,
      (__attribute__((address_space(3))) void*)ldst, 16, 0, 0);
  __builtin_amdgcn_global_load_lds(
      (const __attribute__((address_space(1))) void*)(gsrc + 1024),
      (__attribute__((address_space(3))) void*)(ldst + 1024), 16, 0, 0);
}

// ---------------------------------------------------------------------------
// Main fused kernel v3: round-1 staging structure (B via LDS dbuf, 72 barrier-
// paced 8KB stages) + EXPERT-PAIRING: each stage holds one k-step for a pair
// of experts, so each A-frag ds_read feeds 4 MFMA (2 experts x 2 n-tiles).
// LDS reads/stage/wave: 8 A + 4 B = 12 b128 for 32 MFMA (was 20 for 32).
// ---------------------------------------------------------------------------
__global__ __launch_bounds__(256, 2) void moe_conv_kernel(
    const float* __restrict__ x,
    const float* __restrict__ eb,
    const unsigned short* __restrict__ bp,
    const float* __restrict__ gate,
    float* __restrict__ out) {
  __shared__ __align__(16) char smem[SMEM_BYTES];
  unsigned short* slab = (unsigned short*)smem;
  unsigned short* bbufs = (unsigned short*)(smem + BBUF_OFF);
  float* ldsg = (float*)(smem + LDSG_OFF);   // [pw_local 8][e 8]

  const int tid = threadIdx.x;
  const int bid = blockIdx.x;
  const int wseg = bid & 1;
  const int hq = (bid >> 1) & 31;
  const int b = bid >> 6;
  const int w0 = wseg * 64;
  const int wid = tid >> 6;
  const int lane = tid & 63;
  const int quad = lane >> 4;
  const int l15 = lane & 15;
  const int rp  = wid >> 1;         // row-pair within block
  const int och = wid & 1;          // oc half
  const int ntb = och * 2;          // base n-tile

  // kick off B stage 0 DMA immediately (overlaps slab staging)
  load_stage(bp, smem, 0, 0, wid, lane);

  // gates for this block's 8 patches (4 rows = one patch row hq/2)
  if (tid < 64) {
    ldsg[tid] = gate[((b * 16 + (hq >> 1)) * 16 + wseg * 8 + (tid >> 3)) * 8 + (tid & 7)];
  }

  // --- stage x slab: rows hq*4-1 .. hq*4+4, cols w0-1 .. w0+64, all c ---
  const int hbase = hq * 4 - 1;
  const int wbase = w0 - 1;
  for (int flat = tid; flat < 6 * 32 * COLS; flat += 256) {
    int col = flat % COLS;
    int t = flat / COLS;
    int cp = t & 31;                    // channel pair
    int r = t >> 5;                     // slab row 0..5
    int gh = hbase + r;
    int gw_ = wbase + col;
    float v0 = 0.f, v1 = 0.f;
    if (((unsigned)gh < 128u) && ((unsigned)gw_ < 128u)) {
      const float* px = x + (((b * NCH + cp * 2) * NHH + gh) * NWW + gw_);
      v0 = px[0];
      v1 = px[NHH * NWW];
    }
    unsigned int pk = (unsigned int)f2bf(v0) | ((unsigned int)f2bf(v1) << 16);
    *(unsigned int*)&slab[(r * COLS + col) * CSTR + cp * 2] = pk;
  }
  __syncthreads();    // slab ready + B stage 0 landed

  const v4f vzero = {0.f, 0.f, 0.f, 0.f};
  v4f oacc[8][2];
#pragma unroll
  for (int mt = 0; mt < 8; ++mt) {
    oacc[mt][0] = vzero;
    oacc[mt][1] = vzero;
  }

  // wave-constant part of the A-frag LDS address
  const unsigned short* abase = &slab[(rp * 2 * COLS + l15) * CSTR + quad * 8];

  for (int ep = 0; ep < 4; ++ep) {    // expert pair
    v4f vacc[2][8][2];
#pragma unroll
    for (int mt = 0; mt < 8; ++mt) {
      vacc[0][mt][0] = vzero; vacc[0][mt][1] = vzero;
      vacc[1][mt][0] = vzero; vacc[1][mt][1] = vzero;
    }

#pragma unroll
    for (int sl = 0; sl < KSTEPS; ++sl) {   // k-step within expert pair
      const int gs = ep * KSTEPS + sl;      // flat stage 0..71
      if (gs > 0) __syncthreads();          // stage gs ready; gs-1 consumed
      if (gs + 1 < 72) load_stage(bp, smem, gs + 1, (gs + 1) & 1, wid, lane);

      const unsigned short* bstage = bbufs + (gs & 1) * 4096;
      const int kh = sl / 6;
      const int kw = (sl / 2) % 3;
      const int ch = sl & 1;
      const v8s b00 = *(const v8s*)(bstage + (ntb) * 512 + lane * 8);
      const v8s b01 = *(const v8s*)(bstage + (ntb + 1) * 512 + lane * 8);
      const v8s b10 = *(const v8s*)(bstage + (4 + ntb) * 512 + lane * 8);
      const v8s b11 = *(const v8s*)(bstage + (4 + ntb + 1) * 512 + lane * 8);
      __builtin_amdgcn_s_setprio(1);
#pragma unroll
      for (int mt = 0; mt < 8; ++mt) {
        // row_local = rp*2 + (mt>>2) + kh ; col = (mt&3)*16 + l15 + kw
        const v8s a = *(const v8s*)(abase +
            (((mt >> 2) + kh) * COLS + (mt & 3) * 16 + kw) * CSTR + ch * 32);
        vacc[0][mt][0] = __builtin_amdgcn_mfma_f32_16x16x32_bf16(a, b00, vacc[0][mt][0], 0, 0, 0);
        vacc[0][mt][1] = __builtin_amdgcn_mfma_f32_16x16x32_bf16(a, b01, vacc[0][mt][1], 0, 0, 0);
        vacc[1][mt][0] = __builtin_amdgcn_mfma_f32_16x16x32_bf16(a, b10, vacc[1][mt][0], 0, 0, 0);
        vacc[1][mt][1] = __builtin_amdgcn_mfma_f32_16x16x32_bf16(a, b11, vacc[1][mt][1], 0, 0, 0);
      }
      __builtin_amdgcn_s_setprio(0);
    }

    // epilogue: bias + relu + gate for both experts of the pair
#pragma unroll
    for (int e01 = 0; e01 < 2; ++e01) {
      const int e = ep * 2 + e01;
      float bias0 = eb[e * NOC + ntb * 16 + l15];
      float bias1 = eb[e * NOC + (ntb + 1) * 16 + l15];
#pragma unroll
      for (int mt = 0; mt < 8; ++mt) {
        float g = ldsg[((mt & 3) * 2 + (quad >> 1)) * 8 + e];
#pragma unroll
        for (int r = 0; r < 4; ++r) {
          float v0 = fmaxf(vacc[e01][mt][0][r] + bias0, 0.f);
          float v1 = fmaxf(vacc[e01][mt][1][r] + bias1, 0.f);
          oacc[mt][0][r] += v0 * g;
          oacc[mt][1][r] += v1 * g;
        }
      }
    }
  }

  // ---- transpose through LDS (per-wave region) for full-line stores ----
  __syncthreads();                      // everyone done with slab/B buffers
  float* tb = (float*)smem + wid * 4352;  // [row:2][oc:32][68] floats = 17408 B
#pragma unroll
  for (int i = 0; i < 2; ++i)
#pragma unroll
    for (int mt = 0; mt < 8; ++mt)
      *(v4f*)(tb + (mt >> 2) * 2176 + (i * 16 + l15) * 68 + (mt & 3) * 16 + quad * 4) =
          oacc[mt][i];
  // wave-private region: in-wave lgkmcnt ordering suffices, no barrier

  const int h0 = hq * 4 + rp * 2;
#pragma unroll
  for (int r2 = 0; r2 < 2; ++r2) {
    const int h = h0 + r2;
#pragma unroll
    for (int g4 = 0; g4 < 8; ++g4) {
      const int ocl = g4 * 4 + quad;            // 0..31 within this oc half
      const v4f vv = *(const v4f*)(tb + r2 * 2176 + ocl * 68 + l15 * 4);
      float* dst = out + ((b * NOC + och * 32 + ocl) * NHH + h) * NWW + w0 + l15 * 4;
      *(v4f*)dst = vv;
    }
  }
}

// ---------------------------------------------------------------------------
extern "C" void kernel_launch(void* const* d_in, const int* in_sizes, int n_in,
                              void* d_out, int out_size, void* d_ws, size_t ws_size,
                              hipStream_t stream) {
  const float* x  = (const float*)d_in[0];
  const float* ew = (const float*)d_in[1];
  const float* eb = (const float*)d_in[2];
  const float* gw = (const float*)d_in[3];
  const float* gb = (const float*)d_in[4];
  float* out = (float*)d_out;

  unsigned short* bp = (unsigned short*)d_ws;              // 294912 bf16 = 589824 B
  float* gate = (float*)((char*)d_ws + 589824);            // 4096*8 fp32 = 131072 B

  hipLaunchKernelGGL(pack_b_kernel, dim3(1152), dim3(256), 0, stream, ew, bp);
  hipLaunchKernelGGL(gate_kernel, dim3(256), dim3(512), 0, stream, x, gw, gb, gate);
  hipLaunchKernelGGL(moe_conv_kernel, dim3(1024), dim3(256), 0, stream, x, eb, bp, gate, out);
}

// Round 4
// 276.024 us; speedup vs baseline: 2.8003x; 1.0627x over previous
//
#include <hip/hip_runtime.h>

typedef short v8s __attribute__((ext_vector_type(8)));
typedef float v4f __attribute__((ext_vector_type(4)));

// problem constants
#define NCH    64
#define NHH    128
#define NWW    128
#define NOC    64
#define KSTEPS 18          // 576 / 32

// LDS slab layout: [6 rows][66 cols][72 c (64 + 8 pad)] bf16, bank-swizzled
#define CSTR 72
#define COLS 66
#define SLAB_BYTES (6 * COLS * CSTR * 2)     // 57024
#define BBUF_OFF   SLAB_BYTES                // B triple-buffer at 57024
#define NBUF 3
#define LDSG_OFF   (SLAB_BYTES + NBUF * 8192)  // 81600
#define SMEM_BYTES (LDSG_OFF + 256)            // 81856 (alloc 81920 -> 2 blk/CU)

#define GW_STRIDE 6144

__device__ __forceinline__ unsigned short f2bf(float f) {
  unsigned int u = __float_as_uint(f);
  u += 0x7FFFu + ((u >> 16) & 1u);           // round-to-nearest-even
  return (unsigned short)(u >> 16);
}

// ---------------------------------------------------------------------------
// Pack expert weights into MFMA B-fragment-linear bf16 (round-1 layout):
// element (((e*18+s)*4+nt)*64+lane)*8+j  =  W[k = s*32+(lane>>4)*8+j][n = nt*16+(lane&15)]
// with k = (kh*3+kw)*64 + c  and W[k][n] = expert_w[e][n][c][kh][kw]
// ---------------------------------------------------------------------------
__global__ void pack_b_kernel(const float* __restrict__ ew,
                              unsigned short* __restrict__ bp) {
  int f = blockIdx.x * 256 + threadIdx.x;    // 0 .. 294911
  int j = f & 7;
  int t = f >> 3;
  int lane = t & 63;
  t >>= 6;
  int nt = t & 3;
  t >>= 2;                                   // t = e*18 + s, 0..143
  int s = t % KSTEPS;
  int e = t / KSTEPS;
  int k = s * 32 + (lane >> 4) * 8 + j;
  int n = nt * 16 + (lane & 15);
  int khw = k >> 6;
  int c = k & 63;
  bp[f] = f2bf(ew[((e * NOC + n) * NCH + c) * 9 + khw]);
}

// ---------------------------------------------------------------------------
// Gating v2 (unchanged, known-good): one block per (b, ph), 512 threads.
// ---------------------------------------------------------------------------
__global__ __launch_bounds__(512) void gate_kernel(
    const float* __restrict__ x,
    const float* __restrict__ gw,
    const float* __restrict__ gb,
    float* __restrict__ gate_out) {
  __shared__ float xs[16][8][132];   // 16-ch chunk, 8 rows, 128 cols (+4 pad)
  __shared__ float wsum[8][32];      // pos-part row sums per (expert, feature)
  __shared__ float lg[16][8];        // logits [pw][e]

  const int pid = blockIdx.x;        // b*16 + ph
  const int ph = pid & 15;
  const int b = pid >> 4;
  const int tid = threadIdx.x;
  const int e = tid >> 6;            // expert = wave id
  const int lane = tid & 63;

  // positional row-sums: 256 threads cover (e2, j) = 8 x 32
  if (tid < 256) {
    int e2 = tid >> 5, j = tid & 31;
    const float* p = gw + e2 * GW_STRIDE + 4096 + j * 64;
    float s = 0.f;
#pragma unroll
    for (int g = 0; g < 16; ++g) {
      float4 v = *(const float4*)(p + g * 4);
      s += v.x + v.y + v.z + v.w;
    }
    wsum[e2][j] = s;
  }

  float acc[16];
#pragma unroll
  for (int pw = 0; pw < 16; ++pw) acc[pw] = 0.f;

  const float* xrow = x + ((size_t)(b * NCH) * NHH + ph * 8) * NWW;

  for (int cc = 0; cc < 4; ++cc) {
    __syncthreads();                 // prior chunk fully consumed
    for (int i = tid; i < 4096; i += 512) {
      int c = i >> 8;
      int py = (i >> 5) & 7;
      int w4 = i & 31;
      float4 v = *(const float4*)&xrow[(cc * 16 + c) * (NHH * NWW) + py * NWW + w4 * 4];
      *(float4*)&xs[c][py][w4 * 4] = v;
    }
    __syncthreads();
#pragma unroll
    for (int i = 0; i < 4; ++i) {
      int g = lane + 64 * i;         // 0..255 = (c:16, py:8, pxg:2)
      int pxg = g & 1;
      int py = (g >> 1) & 7;
      int c = g >> 4;
      const float4 wv = *(const float4*)&gw[e * GW_STRIDE + (cc * 16 + c) * 64 + py * 8 + pxg * 4];
      const float* xp = &xs[c][py][pxg * 4];
#pragma unroll
      for (int pw = 0; pw < 16; ++pw) {
        float4 xv = *(const float4*)(xp + pw * 8);
        acc[pw] += xv.x * wv.x + xv.y * wv.y + xv.z * wv.z + xv.w * wv.w;
      }
    }
  }

#pragma unroll
  for (int pw = 0; pw < 16; ++pw) {
    float v = acc[pw];
#pragma unroll
    for (int off = 32; off > 0; off >>= 1) v += __shfl_xor(v, off, 64);
    if (lane == 0) lg[pw][e] = v;
  }
  __syncthreads();

  if (tid < 16) {
    const int pw = tid;
    const float cy = (ph + 0.5f) / 16.0f;
    const float cx = (pw + 0.5f) / 16.0f;
    float l[8];
#pragma unroll
    for (int ee = 0; ee < 8; ++ee) l[ee] = lg[pw][ee] + gb[ee];
    for (int j = 0; j < 32; ++j) {
      float freq = (float)(1 << (j & 7)) * 3.14159265358979323846f;
      float base = (j < 16) ? cy : cx;
      float a = base * freq;
      float v = ((j >> 3) & 1) ? cosf(a) : sinf(a);
#pragma unroll
      for (int ee = 0; ee < 8; ++ee) l[ee] += v * wsum[ee][j];
    }
    float mx = -1e30f;
#pragma unroll
    for (int ee = 0; ee < 8; ++ee) mx = fmaxf(mx, l[ee]);
    float sum = 0.f;
#pragma unroll
    for (int ee = 0; ee < 8; ++ee) { l[ee] = expf(l[ee] - mx); sum += l[ee]; }
    float inv = 1.0f / sum;
#pragma unroll
    for (int ee = 0; ee < 8; ++ee)
      gate_out[(pid * 16 + pw) * 8 + ee] = l[ee] * inv;   // [b][ph][pw][e]
  }
}

// ---------------------------------------------------------------------------
// Async-stage one B stage (2 k-steps = 8 KB) into LDS buffer `buf` (0..2).
// Each wave DMAs its 2 KB quarter with two global_load_lds width-16 ops.
// ---------------------------------------------------------------------------
__device__ __forceinline__ void load_stage(const unsigned short* __restrict__ bp,
                                           char* smem, int gs, int buf,
                                           int wid, int lane) {
  const char* gsrc = (const char*)bp + gs * 8192 + wid * 2048 + lane * 16;
  char* ldst = smem + BBUF_OFF + buf * 8192 + wid * 2048;   // wave-uniform base
  __builtin_amdgcn_global_load_lds(
      (const __attribute__((address_space(1))) void*)gsrc,
      (__attribute__((address_space(3))) void*)ldst, 16, 0, 0);
  __builtin_amdgcn_global_load_lds(
      (const __attribute__((address_space(1))) void*)(gsrc + 1024),
      (__attribute__((address_space(3))) void*)(ldst + 1024), 16, 0, 0);
}

// ---------------------------------------------------------------------------
// Main fused kernel v4: block = 4 waves (256 thr), 4 rows x 64 cols x 64 oc.
// Wave wid owns ONE row (hq*4+wid) x 64 cols x ALL 64 oc: per k-step 4 A-frag
// ds_reads are shared across 4 n-tiles (16 MFMA) -> 0.5 LDS reads/MFMA, and
// vacc is only 4x4 v4f (64 regs, no spill).
// A-slab is bank-swizzled (within-row byte += (row&7)<<4 mod 128) -> the
// stride-144 conflict classes are spread perfectly (8 lanes / 4-bank group).
// B pipeline: 3-deep LDS buffers, counted `s_waitcnt vmcnt(2)` + raw barrier
// (never drains to 0 in the loop); prefetch issued AFTER the barrier so the
// buffer being overwritten (gs-1 mod 3) is provably consumed by all waves.
// ---------------------------------------------------------------------------
__global__ __launch_bounds__(256, 2) void moe_conv_kernel(
    const float* __restrict__ x,
    const float* __restrict__ eb,
    const unsigned short* __restrict__ bp,
    const float* __restrict__ gate,
    float* __restrict__ out) {
  __shared__ __align__(16) char smem[SMEM_BYTES];
  unsigned short* slab = (unsigned short*)smem;
  unsigned short* bbufs = (unsigned short*)(smem + BBUF_OFF);
  float* ldsg = (float*)(smem + LDSG_OFF);   // [pw_local 8][e 8]

  const int tid = threadIdx.x;
  const int bid = blockIdx.x;
  const int wseg = bid & 1;
  const int hq = (bid >> 1) & 31;
  const int b = bid >> 6;
  const int w0 = wseg * 64;
  const int wid = tid >> 6;
  const int lane = tid & 63;
  const int quad = lane >> 4;
  const int l15 = lane & 15;

  // kick off B stage 0 DMA immediately (overlaps slab staging)
  load_stage(bp, smem, 0, 0, wid, lane);

  // gates for this block's 8 patches (4 rows = one patch row hq/2)
  if (tid < 64) {
    ldsg[tid] = gate[((b * 16 + (hq >> 1)) * 16 + wseg * 8 + (tid >> 3)) * 8 + (tid & 7)];
  }

  // --- stage x slab: rows hq*4-1 .. hq*4+4, cols w0-1 .. w0+64, all c ---
  // bank swizzle: within-row byte = (cp*4 + ((srow&7)<<4)) & 127
  const int hbase = hq * 4 - 1;
  const int wbase = w0 - 1;
  for (int flat = tid; flat < 6 * 32 * COLS; flat += 256) {
    int col = flat % COLS;
    int t = flat / COLS;
    int cp = t & 31;                    // channel pair
    int r = t >> 5;                     // slab row 0..5
    int gh = hbase + r;
    int gw_ = wbase + col;
    float v0 = 0.f, v1 = 0.f;
    if (((unsigned)gh < 128u) && ((unsigned)gw_ < 128u)) {
      const float* px = x + (((b * NCH + cp * 2) * NHH + gh) * NWW + gw_);
      v0 = px[0];
      v1 = px[NHH * NWW];
    }
    unsigned int pk = (unsigned int)f2bf(v0) | ((unsigned int)f2bf(v1) << 16);
    int srow = r * COLS + col;
    int boff = ((cp * 4) + ((srow & 7) << 4)) & 127;
    *(unsigned int*)((char*)slab + srow * 144 + boff) = pk;
  }

  // B stage 1 DMA before the slab barrier (barrier drains both, pipeline ok)
  load_stage(bp, smem, 1, 1, wid, lane);
  __syncthreads();    // slab ready + B stages 0,1 landed (full drain, once)

  const v4f vzero = {0.f, 0.f, 0.f, 0.f};
  v4f oacc[4][4];
#pragma unroll
  for (int mt = 0; mt < 4; ++mt)
#pragma unroll
    for (int nt = 0; nt < 4; ++nt) oacc[mt][nt] = vzero;

  // wave/lane constants for A addressing
  const int q16 = quad * 16;
  const int lw  = l15 + 2 * wid;                 // for (srow&7) at read
  const int rowb = (wid * COLS + l15) * 144;     // byte base (kh=kw=0)

  for (int e = 0; e < 8; ++e) {
    v4f vacc[4][4];
#pragma unroll
    for (int mt = 0; mt < 4; ++mt)
#pragma unroll
      for (int nt = 0; nt < 4; ++nt) vacc[mt][nt] = vzero;

#pragma unroll
    for (int st = 0; st < 9; ++st) {
      const int gs = e * 9 + st;        // flat stage 0..71
      if (gs > 0) {
        asm volatile("s_waitcnt vmcnt(2)" ::: "memory");  // stage gs landed
        __builtin_amdgcn_s_barrier();                     // all waves agree
        __builtin_amdgcn_sched_barrier(0);
      }
      // prefetch stage gs+2 (clamped dummy at tail keeps vmcnt uniform);
      // target buffer (gs+2)%3 == (gs-1)%3 was consumed before this barrier
      {
        const int g2 = gs + 2;
        const int gsrc = (g2 < 72) ? g2 : 71;
        load_stage(bp, smem, gsrc, (st + 2) % 3, wid, lane);
      }

      const unsigned short* bstage = bbufs + (st % 3) * 4096;
#pragma unroll
      for (int sub = 0; sub < 2; ++sub) {
        const int sl = st * 2 + sub;    // expert-local k-step 0..17
        const int kh = sl / 6;
        const int kw = (sl / 2) % 3;
        const int ch = sl & 1;
        v8s bf[4];
#pragma unroll
        for (int nt = 0; nt < 4; ++nt)
          bf[nt] = *(const v8s*)(bstage + (sub * 4 + nt) * 512 + lane * 8);
        // A byte address: row = (wid+kh)*COLS + mt*16 + l15 + kw
        // swizzled channel offset = (q16 + ch*64 + ((row&7)<<4)) & 127
        const int rot = ((lw + 2 * kh + kw) & 7) << 4;
        const int aoff = (q16 + ch * 64 + rot) & 127;
        const char* arow = (const char*)slab + rowb + (kh * COLS + kw) * 144 + aoff;
        __builtin_amdgcn_s_setprio(1);
#pragma unroll
        for (int mt = 0; mt < 4; ++mt) {
          const v8s a = *(const v8s*)(arow + mt * 2304);
#pragma unroll
          for (int nt = 0; nt < 4; ++nt)
            vacc[mt][nt] = __builtin_amdgcn_mfma_f32_16x16x32_bf16(a, bf[nt], vacc[mt][nt], 0, 0, 0);
        }
        __builtin_amdgcn_s_setprio(0);
      }
    }

    // epilogue: bias + relu + gate, accumulate into oacc (wave-private)
    float bias[4];
#pragma unroll
    for (int nt = 0; nt < 4; ++nt) bias[nt] = eb[e * NOC + nt * 16 + l15];
#pragma unroll
    for (int mt = 0; mt < 4; ++mt) {
      float g = ldsg[(mt * 2 + (quad >> 1)) * 8 + e];
#pragma unroll
      for (int nt = 0; nt < 4; ++nt)
#pragma unroll
        for (int r = 0; r < 4; ++r) {
          float v = fmaxf(vacc[mt][nt][r] + bias[nt], 0.f);
          oacc[mt][nt][r] += v * g;
        }
    }
  }

  // ---- transpose through LDS (per-wave region) for full-line stores ----
  // D-frag mapping: m (pixel col) = mt*16 + quad*4 + r ; n (oc) = nt*16 + l15
  __syncthreads();                      // everyone done with slab/B buffers
  float* tb = (float*)smem + wid * 4352;  // [oc:64][68] floats = 17408 B
#pragma unroll
  for (int mt = 0; mt < 4; ++mt)
#pragma unroll
    for (int nt = 0; nt < 4; ++nt)
      *(v4f*)(tb + (nt * 16 + l15) * 68 + mt * 16 + quad * 4) = oacc[mt][nt];
  // wave-private region: in-wave lgkmcnt ordering suffices, no barrier

  const int h = hq * 4 + wid;
#pragma unroll
  for (int g4 = 0; g4 < 16; ++g4) {
    const int ocl = g4 * 4 + quad;              // 0..63
    const v4f vv = *(const v4f*)(tb + ocl * 68 + l15 * 4);
    float* dst = out + ((b * NOC + ocl) * NHH + h) * NWW + w0 + l15 * 4;
    *(v4f*)dst = vv;
  }
}

// ---------------------------------------------------------------------------
extern "C" void kernel_launch(void* const* d_in, const int* in_sizes, int n_in,
                              void* d_out, int out_size, void* d_ws, size_t ws_size,
                              hipStream_t stream) {
  const float* x  = (const float*)d_in[0];
  const float* ew = (const float*)d_in[1];
  const float* eb = (const float*)d_in[2];
  const float* gw = (const float*)d_in[3];
  const float* gb = (const float*)d_in[4];
  float* out = (float*)d_out;

  unsigned short* bp = (unsigned short*)d_ws;              // 294912 bf16 = 589824 B
  float* gate = (float*)((char*)d_ws + 589824);            // 4096*8 fp32 = 131072 B

  hipLaunchKernelGGL(pack_b_kernel, dim3(1152), dim3(256), 0, stream, ew, bp);
  hipLaunchKernelGGL(gate_kernel, dim3(256), dim3(512), 0, stream, x, gw, gb, gate);
  hipLaunchKernelGGL(moe_conv_kernel, dim3(1024), dim3(256), 0, stream, x, eb, bp, gate, out);
}